// Round 3
// baseline (366.141 us; speedup 1.0000x reference)
//
#include <hip/hip_runtime.h>
#include <math.h>

// Problem constants
#define BB    512
#define NNODE 64
#define LLEN  64
#define DD    100
#define NNODES 50000
#define NM1   49999     // n_nodes - 1
#define KP    128       // padded K for emb/h (4 k-steps of 32)
#define KAV   224       // padded K for av section (7 k-steps)
#define KTOT  352       // KAV + KP
#define NCB   391       // ceil(49999/128) logits col-blocks
#define SHIFT 20.0f

typedef __attribute__((ext_vector_type(8))) short short8;
typedef __attribute__((ext_vector_type(4))) short short4_t;
typedef __attribute__((ext_vector_type(4))) float f32x4;
typedef unsigned short ushort_t;

__device__ __forceinline__ float sigm(float x) { return 1.0f / (1.0f + __expf(-x)); }
__device__ __forceinline__ float mytanh(float x) {
  x = fminf(15.0f, fmaxf(-15.0f, x));
  float e = __expf(-2.0f * x);
  return (1.0f - e) / (1.0f + e);
}
__device__ __forceinline__ float f4c(const float4& v, int k) { return ((const float*)&v)[k]; }
__device__ __forceinline__ ushort_t f2bf(float f) {  // RNE float->bf16
  union { float f; unsigned u; } v; v.f = f;
  unsigned r = v.u + 0x7FFF + ((v.u >> 16) & 1);
  return (ushort_t)(r >> 16);
}
__device__ __forceinline__ float bf2f(ushort_t s) {
  union { unsigned u; float f; } v; v.u = ((unsigned)s) << 16;
  return v.f;
}
__device__ __forceinline__ short8 cvt8(const float* __restrict__ p) {
  float4 v0 = *(const float4*)p, v1 = *(const float4*)(p + 4);
  short8 r;
  r[0] = (short)f2bf(v0.x); r[1] = (short)f2bf(v0.y);
  r[2] = (short)f2bf(v0.z); r[3] = (short)f2bf(v0.w);
  r[4] = (short)f2bf(v1.x); r[5] = (short)f2bf(v1.y);
  r[6] = (short)f2bf(v1.z); r[7] = (short)f2bf(v1.w);
  return r;
}

// ---------------------------------------------------------------------------
// C0: emb (fp32 [50000][100]) -> eb2 (bf16 [50000][128], zero-padded cols)
// ---------------------------------------------------------------------------
__global__ __launch_bounds__(256) void k_cvt_emb2(
    const float* __restrict__ emb, ushort_t* __restrict__ eb2)
{
  const int tid = blockIdx.x * 256 + threadIdx.x;
  const int r = tid >> 5, c4 = (tid & 31) * 4;
  if (r >= NNODES) return;
  short4_t o = {0, 0, 0, 0};
  if (c4 < DD) {
    float4 v = *(const float4*)(emb + (size_t)r * DD + c4);
    o.x = (short)f2bf(f4c(v, 0)); o.y = (short)f2bf(f4c(v, 1));
    o.z = (short)f2bf(f4c(v, 2)); o.w = (short)f2bf(f4c(v, 3));
  }
  *(short4_t*)(eb2 + (size_t)r * KP + c4) = o;
}

// ---------------------------------------------------------------------------
// C1: weights -> transposed zero-padded bf16 (same as R2).
// ---------------------------------------------------------------------------
__global__ __launch_bounds__(256) void k_cvt_w(
    const float* __restrict__ Wi, const float* __restrict__ Wo,
    const float* __restrict__ gk, const float* __restrict__ ck,
    ushort_t* __restrict__ WioT, ushort_t* __restrict__ gkT,
    ushort_t* __restrict__ ckT)
{
  const int idx = blockIdx.x * 256 + threadIdx.x;
  const int y = blockIdx.y;
  if (y == 0) {
    if (idx >= 208 * 128) return;
    int n = idx >> 7, k = idx & 127;
    float v = 0.0f;
    if (k < DD) {
      if (n < 100) v = Wi[k * DD + n];
      else if (n < 200) v = Wo[k * DD + (n - 100)];
    }
    WioT[idx] = f2bf(v);
  } else if (y == 1) {
    if (idx >= 208 * KTOT) return;
    int n = idx / KTOT, k = idx - n * KTOT;
    float v = 0.0f;
    if (n < 200) {
      if (k < KAV) { if (k < 200) v = gk[k * 200 + n]; }
      else { int kk = k - KAV; if (kk < 100) v = gk[(200 + kk) * 200 + n]; }
    }
    gkT[idx] = f2bf(v);
  } else {
    if (idx >= 112 * KTOT) return;
    int n = idx / KTOT, k = idx - n * KTOT;
    float v = 0.0f;
    if (n < 100) {
      if (k < KAV) { if (k < 200) v = ck[k * DD + n]; }
      else { int kk = k - KAV; if (kk < 100) v = ck[(200 + kk) * DD + n]; }
    }
    ckT[idx] = f2bf(v);
  }
}

// ---------------------------------------------------------------------------
// K1: fused fio + av per batch. Block = batch b (64 rows, 4 waves).
// Phase 1: fi/fo = gather(eb2,item)@[Wi|Wo]+bias -> LDS s_f[2][112][72] bf16.
// Phase 2: av = [adj_in@fi | adj_out@fo] (adj converted in-register) -> avb.
// ---------------------------------------------------------------------------
__global__ __launch_bounds__(256) void k_fio_av(
    const ushort_t* __restrict__ eb2, const int* __restrict__ item,
    const ushort_t* __restrict__ WioT,
    const float* __restrict__ bi, const float* __restrict__ bo,
    const float* __restrict__ adj_in, const float* __restrict__ adj_out,
    ushort_t* __restrict__ avb)
{
  __shared__ ushort_t s_f[2][112][72];   // [fi|fo][avcol][node], +8 pad
  const int t = threadIdx.x, wave = t >> 6, lane = t & 63;
  const int n16 = lane & 15, quad = lane >> 4;
  const int b = blockIdx.x;
  const int m0 = b * 64 + wave * 16;

  // zero pad rows 100..111 (multiplied into discarded av cols, but keep clean)
  for (int idx = t; idx < 2 * 12 * 64; idx += 256) {
    int which = idx / 768, rem = idx - which * 768;
    s_f[which][100 + rem / 64][rem & 63] = 0;
  }

  // ---- Phase 1: fio ----
  const ushort_t* arow = eb2 + (size_t)item[m0 + n16] * KP + quad * 8;
  short8 af[4];
#pragma unroll
  for (int ks = 0; ks < 4; ++ks) af[ks] = *(const short8*)(arow + ks * 32);

  const int node0 = wave * 16 + quad * 4;
#pragma unroll
  for (int sub = 0; sub < 13; ++sub) {
    const ushort_t* brow = WioT + (size_t)(sub * 16 + n16) * KP + quad * 8;
    f32x4 acc = {0.0f, 0.0f, 0.0f, 0.0f};
#pragma unroll
    for (int ks = 0; ks < 4; ++ks)
      acc = __builtin_amdgcn_mfma_f32_16x16x32_bf16(af[ks], *(const short8*)(brow + ks * 32), acc, 0, 0, 0);
    const int col = sub * 16 + n16;
    if (col < 200) {
      const float bias = (col < 100) ? bi[col] : bo[col - 100];
      short4_t st;
#pragma unroll
      for (int r = 0; r < 4; ++r) ((ushort_t*)&st)[r] = f2bf(acc[r] + bias);
      const int which = (col < 100) ? 0 : 1;
      const int c = (col < 100) ? col : col - 100;
      *(short4_t*)&s_f[which][c][node0] = st;
    }
  }
  __syncthreads();

  // ---- Phase 2: av ----
  const float* aI = adj_in  + ((size_t)b * 64 + wave * 16 + n16) * 64 + quad * 8;
  const float* aO = adj_out + ((size_t)b * 64 + wave * 16 + n16) * 64 + quad * 8;
  short8 afI[2], afO[2];
#pragma unroll
  for (int ks = 0; ks < 2; ++ks) {
    afI[ks] = cvt8(aI + ks * 32);
    afO[ks] = cvt8(aO + ks * 32);
  }
#pragma unroll
  for (int sub = 0; sub < 7; ++sub) {
    const int col = sub * 16 + n16;
    const ushort_t* bI = &s_f[0][col][quad * 8];
    const ushort_t* bO = &s_f[1][col][quad * 8];
    f32x4 accI = {0, 0, 0, 0}, accO = {0, 0, 0, 0};
#pragma unroll
    for (int ks = 0; ks < 2; ++ks) {
      accI = __builtin_amdgcn_mfma_f32_16x16x32_bf16(afI[ks], *(const short8*)(bI + ks * 32), accI, 0, 0, 0);
      accO = __builtin_amdgcn_mfma_f32_16x16x32_bf16(afO[ks], *(const short8*)(bO + ks * 32), accO, 0, 0, 0);
    }
    if (col < 100) {
#pragma unroll
      for (int r = 0; r < 4; ++r) {
        const size_t row = (size_t)b * 64 + wave * 16 + quad * 4 + r;
        avb[row * KAV + col] = f2bf(accI[r]);
        avb[row * KAV + 100 + col] = f2bf(accO[r]);
      }
    }
  }
}

// ---------------------------------------------------------------------------
// K2: fused GRU via MFMA (padded LDS rows: 136 shorts, conflict-free b128).
// ---------------------------------------------------------------------------
__global__ __launch_bounds__(256) void k_gru_mfma(
    const ushort_t* __restrict__ avb, const ushort_t* __restrict__ eb2,
    const int* __restrict__ item,
    const ushort_t* __restrict__ gkT, const float* __restrict__ gb,
    const ushort_t* __restrict__ ckT, const float* __restrict__ cbs,
    float* __restrict__ fin2)
{
  __shared__ ushort_t s_h[4][16][136];
  __shared__ ushort_t s_rh[4][16][136];
  __shared__ float    s_u[4][16][104];
  const int t = threadIdx.x, wave = t >> 6, lane = t & 63;
  const int n16 = lane & 15, quad = lane >> 4;
  const int m0 = (blockIdx.x * 4 + wave) * 16;

  // stage h rows into LDS (bf16) + zero rh pad cols 100..127
  {
    const int row_s = lane & 15, chunk = lane >> 4;
    const ushort_t* hsrc = eb2 + (size_t)item[m0 + row_s] * KP + chunk * 32;
#pragma unroll
    for (int j = 0; j < 4; ++j)
      *(short8*)&s_h[wave][row_s][chunk * 32 + j * 8] = *(const short8*)(hsrc + j * 8);
#pragma unroll
    for (int j = 0; j < 7; ++j)
      s_rh[wave][row_s][100 + chunk * 7 + j] = 0;
  }

  const ushort_t* avrow = avb + (size_t)(m0 + n16) * KAV + quad * 8;
  short8 afa[7];
#pragma unroll
  for (int ks = 0; ks < 7; ++ks) afa[ks] = *(const short8*)(avrow + ks * 32);
  const ushort_t* hrow = eb2 + (size_t)item[m0 + n16] * KP + quad * 8;
  short8 afh[4];
#pragma unroll
  for (int ks = 0; ks < 4; ++ks) afh[ks] = *(const short8*)(hrow + ks * 32);
  __syncthreads();

  // Phase 1: gates
#pragma unroll
  for (int sub = 0; sub < 13; ++sub) {
    const ushort_t* brow = gkT + (size_t)(sub * 16 + n16) * KTOT + quad * 8;
    f32x4 acc = {0, 0, 0, 0};
#pragma unroll
    for (int ks = 0; ks < 7; ++ks)
      acc = __builtin_amdgcn_mfma_f32_16x16x32_bf16(afa[ks], *(const short8*)(brow + ks * 32), acc, 0, 0, 0);
#pragma unroll
    for (int ks = 0; ks < 4; ++ks)
      acc = __builtin_amdgcn_mfma_f32_16x16x32_bf16(afh[ks], *(const short8*)(brow + KAV + ks * 32), acc, 0, 0, 0);
    const int col = sub * 16 + n16;
    if (col < 200) {
      const float bias = gb[col];
#pragma unroll
      for (int r = 0; r < 4; ++r) {
        const int row = quad * 4 + r;
        const float g = sigm(acc[r] + bias);
        if (col < 100) {
          s_rh[wave][row][col] = f2bf(g * bf2f(s_h[wave][row][col]));
        } else {
          s_u[wave][row][col - 100] = g;
        }
      }
    }
  }
  __syncthreads();

  // Phase 2: candidate + output
  short8 afr[4];
#pragma unroll
  for (int ks = 0; ks < 4; ++ks) afr[ks] = *(const short8*)&s_rh[wave][n16][ks * 32];
#pragma unroll
  for (int sub = 0; sub < 7; ++sub) {
    const ushort_t* brow = ckT + (size_t)(sub * 16 + n16) * KTOT + quad * 8;
    f32x4 acc = {0, 0, 0, 0};
#pragma unroll
    for (int ks = 0; ks < 7; ++ks)
      acc = __builtin_amdgcn_mfma_f32_16x16x32_bf16(afa[ks], *(const short8*)(brow + ks * 32), acc, 0, 0, 0);
#pragma unroll
    for (int ks = 0; ks < 4; ++ks)
      acc = __builtin_amdgcn_mfma_f32_16x16x32_bf16(afr[ks], *(const short8*)(brow + KAV + ks * 32), acc, 0, 0, 0);
    const int col = sub * 16 + n16;
    if (col < 100) {
      const float bias = cbs[col];
#pragma unroll
      for (int r = 0; r < 4; ++r) {
        const int row = quad * 4 + r;
        const float c = mytanh(acc[r] + bias);
        const float u = s_u[wave][row][col];
        const float hv = bf2f(s_h[wave][row][col]);
        fin2[(size_t)(m0 + row) * DD + col] = u * hv + (1.0f - u) * c;
      }
    }
  }
}

// ---------------------------------------------------------------------------
// K3: attention readout -> mab[b][128] bf16 (zero-padded k>=100)
// ---------------------------------------------------------------------------
__global__ __launch_bounds__(256) void k_attn(
    const float* __restrict__ fin2, const int* __restrict__ alias_,
    const float* __restrict__ mask,
    const float* __restrict__ w1, const float* __restrict__ w2,
    const float* __restrict__ nv, const float* __restrict__ nb,
    ushort_t* __restrict__ mab)
{
  __shared__ float s_seqh[NNODE * DD];
  __shared__ float s_m[NNODE * DD];
  __shared__ float s_last[DD];
  __shared__ float s_coef[NNODE];
  __shared__ int s_lastid;
  const int b = blockIdx.x, t = threadIdx.x;

  if (t == 0) {
    float s = 0.0f;
    for (int l = 0; l < LLEN; ++l) s += mask[b * LLEN + l];
    int rm = (int)(s + 0.5f);
    s_lastid = alias_[b * LLEN + rm - 1];
  }
  for (int idx = t; idx < NNODE * DD; idx += 256) {
    int l = idx / DD, d = idx - l * DD;
    int n = alias_[b * LLEN + l];
    s_seqh[idx] = fin2[((size_t)b * NNODE + n) * DD + d];
  }
  __syncthreads();

  if (t < DD) {
    const float* lh = fin2 + ((size_t)b * NNODE + s_lastid) * DD;
    float acc = 0.0f;
    for (int k = 0; k < DD; ++k) acc += lh[k] * w1[k * DD + t];
    s_last[t] = acc;
  }
  __syncthreads();

  {
    const int tx = t & 31, ty = t >> 5, cb4 = tx * 4;
    if (cb4 < DD) {
      float acc[8][4] = {};
      for (int k4 = 0; k4 < 25; ++k4) {
        float4 bv[4];
#pragma unroll
        for (int kk = 0; kk < 4; ++kk) bv[kk] = *(const float4*)(w2 + (size_t)(k4 * 4 + kk) * DD + cb4);
#pragma unroll
        for (int i = 0; i < 8; ++i) {
          float4 a = *(const float4*)(&s_seqh[(ty * 8 + i) * DD + k4 * 4]);
#pragma unroll
          for (int kk = 0; kk < 4; ++kk) {
            float av_ = f4c(a, kk);
#pragma unroll
            for (int j = 0; j < 4; ++j) acc[i][j] += av_ * f4c(bv[kk], j);
          }
        }
      }
#pragma unroll
      for (int i = 0; i < 8; ++i) {
        int l = ty * 8 + i;
#pragma unroll
        for (int j = 0; j < 4; ++j) {
          int e = cb4 + j;
          s_m[l * DD + e] = sigm(acc[i][j] + s_last[e] + nb[e]);
        }
      }
    }
  }
  __syncthreads();

  if (t < LLEN) {
    float acc = 0.0f;
    for (int e = 0; e < DD; ++e) acc += s_m[t * DD + e] * nv[e];
    s_coef[t] = acc * mask[b * LLEN + t];
  }
  __syncthreads();

  if (t < DD) {
    float acc = 0.0f;
    for (int l = 0; l < LLEN; ++l) acc += s_coef[l] * s_seqh[l * DD + t];
    mab[(size_t)b * KP + t] = f2bf(acc);
  } else if (t < KP) {
    mab[(size_t)b * KP + t] = 0;
  }
}

// ---------------------------------------------------------------------------
// K4: logits = mab @ eb2[1:]^T via MFMA — LDS-free version.
//
// Round-2 post-mortem: XCD swizzle cut FETCH 50->6.8 MB but time was
// unchanged (65 us): the kernel is LATENCY-bound at 16% issue utilization.
// The 33 KB LDS C-tile capped residency at 4 blocks/CU (Occupancy 35%),
// and VGPR_Count=52 shows no loads were kept in flight across subs.
//
// This version: (1) no LDS C-tile / no barrier — MFMA fragments are stored
// DIRECTLY: per (sub,r) each quad's 16 lanes write one fully-covered 64 B
// cache-line segment (4 segments per wave store instruction). (2) one-sub-
// ahead register prefetch of eb2 fragments (compile-time-indexed double
// buffer under full unroll). LDS=0 lifts residency to the wave/VGPR limit
// (~6-8 blocks/CU), and prefetch overlaps the L2/LLC load latency with the
// MFMA chain. XCD-ownership swizzle retained from round 2.
// ---------------------------------------------------------------------------
__global__ __launch_bounds__(256) void k_logits_mfma(
    const ushort_t* __restrict__ eb2, const ushort_t* __restrict__ mab,
    float* __restrict__ out, float* __restrict__ sump)
{
  const int t = threadIdx.x;
  const int wave = t >> 6, lane = t & 63;
  const int n16 = lane & 15, quad = lane >> 4;
  const int bid = blockIdx.x;
  const int xcd = bid & 7;
  const int j = bid >> 3;                 // 0..391
  const int stripe = j & 7;               // fast-varying: 8 stripes of a
  const int grp = j >> 3;                 //   cblk are temporally adjacent
  const int cblk = xcd * 49 + grp;        // contiguous 49-cblk chunk per XCD
  if (cblk >= NCB) return;                // 8 tail blocks (xcd=7, grp=48)
  const int m0 = stripe * 64 + wave * 16;

  short8 afr[4];
  const ushort_t* abase = mab + (size_t)(m0 + n16) * KP + quad * 8;
#pragma unroll
  for (int ks = 0; ks < 4; ++ks) afr[ks] = *(const short8*)(abase + ks * 32);

  float* lg = out + 1;
  const int row0 = m0 + quad * 4;         // this lane's 4 output rows

  // prefetch sub 0's B fragments
  short8 bfr[2][4];
  {
    const int c = cblk * 128 + n16;
    const ushort_t* bb = eb2 + (size_t)((c < NM1) ? (c + 1) : 0) * KP + quad * 8;
#pragma unroll
    for (int ks = 0; ks < 4; ++ks) bfr[0][ks] = *(const short8*)(bb + ks * 32);
  }

  float s[4] = {0.0f, 0.0f, 0.0f, 0.0f};
#pragma unroll
  for (int sub = 0; sub < 8; ++sub) {
    // prefetch sub+1 while current MFMAs run
    if (sub < 7) {
      const int cn = cblk * 128 + (sub + 1) * 16 + n16;
      const ushort_t* bb = eb2 + (size_t)((cn < NM1) ? (cn + 1) : 0) * KP + quad * 8;
#pragma unroll
      for (int ks = 0; ks < 4; ++ks) bfr[(sub + 1) & 1][ks] = *(const short8*)(bb + ks * 32);
    }
    f32x4 acc = {0.0f, 0.0f, 0.0f, 0.0f};
#pragma unroll
    for (int ks = 0; ks < 4; ++ks)
      acc = __builtin_amdgcn_mfma_f32_16x16x32_bf16(afr[ks], bfr[sub & 1][ks], acc, 0, 0, 0);
    const int c = cblk * 128 + sub * 16 + n16;
    if (c < NM1) {
#pragma unroll
      for (int r = 0; r < 4; ++r) {
        __builtin_nontemporal_store(acc[r], lg + (size_t)(row0 + r) * NM1 + c);
        s[r] += __expf(acc[r] - SHIFT);
      }
    }
  }
#pragma unroll
  for (int r = 0; r < 4; ++r) {
    float x = s[r];
    x += __shfl_xor(x, 1, 64);
    x += __shfl_xor(x, 2, 64);
    x += __shfl_xor(x, 4, 64);
    x += __shfl_xor(x, 8, 64);
    if (n16 == 0) sump[(size_t)(row0 + r) * NCB + cblk] = x;
  }
}

// ---------------------------------------------------------------------------
// K5: rowterm[r] = logits[r][tar[r]-1] - (log(sum) + SHIFT)
// ---------------------------------------------------------------------------
__global__ __launch_bounds__(64) void k_lse(
    const float* __restrict__ sump, const float* __restrict__ out,
    const int* __restrict__ tar, float* __restrict__ rowterm)
{
  const int r = blockIdx.x, t = threadIdx.x;
  float s = 0.0f;
  for (int i = t; i < NCB; i += 64) s += sump[(size_t)r * NCB + i];
  for (int m = 1; m < 64; m <<= 1) s += __shfl_xor(s, m, 64);
  if (t == 0) {
    int label = tar[r] - 1;
    const float* lg = out + 1;
    rowterm[r] = lg[(size_t)r * NM1 + label] - (logf(s) + SHIFT);
  }
}

// ---------------------------------------------------------------------------
// K6: loss = -mean(rowterm)
// ---------------------------------------------------------------------------
__global__ __launch_bounds__(256) void k_loss(
    const float* __restrict__ rowterm, float* __restrict__ out)
{
  const int t = threadIdx.x;
  __shared__ float red[4];
  float s = rowterm[t] + rowterm[t + 256];
  for (int m = 1; m < 64; m <<= 1) s += __shfl_xor(s, m, 64);
  if ((t & 63) == 0) red[t >> 6] = s;
  __syncthreads();
  if (t == 0) out[0] = -(red[0] + red[1] + red[2] + red[3]) / (float)BB;
}

// ---------------------------------------------------------------------------
extern "C" void kernel_launch(void* const* d_in, const int* in_sizes, int n_in,
                              void* d_out, int out_size, void* d_ws, size_t ws_size,
                              hipStream_t stream)
{
  (void)in_sizes; (void)n_in; (void)out_size; (void)ws_size;
  const float* adj_in  = (const float*)d_in[0];
  const float* adj_out = (const float*)d_in[1];
  const int*   item    = (const int*)d_in[2];
  const int*   alias_  = (const int*)d_in[3];
  const float* mask    = (const float*)d_in[4];
  const int*   tar     = (const int*)d_in[5];
  const float* emb     = (const float*)d_in[6];
  const float* W_in    = (const float*)d_in[7];
  const float* b_in    = (const float*)d_in[8];
  const float* W_out   = (const float*)d_in[9];
  const float* b_out   = (const float*)d_in[10];
  const float* gk      = (const float*)d_in[11];
  const float* gb      = (const float*)d_in[12];
  const float* ck      = (const float*)d_in[13];
  const float* cbs     = (const float*)d_in[14];
  const float* w1      = (const float*)d_in[15];
  const float* w2      = (const float*)d_in[16];
  const float* nv      = (const float*)d_in[17];
  const float* nb      = (const float*)d_in[18];
  float* out = (float*)d_out;

  // Workspace layout, ushort units.
  ushort_t* usw = (ushort_t*)d_ws;
  ushort_t* eb2  = usw;                    // 50000*128     = 6,400,000
  ushort_t* avb  = usw + 6400000;          // 32768*224     = 7,340,032
  ushort_t* WioT = usw + 13740032;         // 208*128       = 26,624
  ushort_t* gkT  = usw + 13766656;         // 208*352       = 73,216
  ushort_t* ckT  = usw + 13839872;         // 112*352       = 39,424
  ushort_t* mab  = usw + 13879296;         // 512*128       = 65,536
  float* fpool   = (float*)(usw + 13944832);
  float* fin2    = fpool;                  // 32768*100     = 3,276,800
  float* sump    = fpool + 3276800;        // 512*391       = 200,192
  float* rowterm = fpool + 3276800 + 200192;   // 512

  k_cvt_emb2<<<dim3(6250), 256, 0, stream>>>(emb, eb2);
  k_cvt_w   <<<dim3(287, 3), 256, 0, stream>>>(W_in, W_out, gk, ck, WioT, gkT, ckT);
  k_fio_av  <<<dim3(512), 256, 0, stream>>>(eb2, item, WioT, b_in, b_out, adj_in, adj_out, avb);
  k_gru_mfma<<<dim3(512), 256, 0, stream>>>(avb, eb2, item, gkT, gb, ckT, cbs, fin2);
  k_attn    <<<dim3(512), 256, 0, stream>>>(fin2, alias_, mask, w1, w2, nv, nb, mab);
  k_logits_mfma<<<dim3(3136), 256, 0, stream>>>(eb2, mab, out, sump);
  k_lse     <<<dim3(512), 64, 0, stream>>>(sump, out, tar, rowterm);
  k_loss    <<<dim3(1), 256, 0, stream>>>(rowterm, out);
}

// Round 4
// 325.740 us; speedup vs baseline: 1.1240x; 1.1240x over previous
//
#include <hip/hip_runtime.h>
#include <math.h>

// Problem constants
#define BB    512
#define NNODE 64
#define LLEN  64
#define DD    100
#define NNODES 50000
#define NM1   49999     // n_nodes - 1
#define KP    128       // padded K for emb/h (4 k-steps of 32)
#define KAV   224       // padded K for av section (7 k-steps)
#define KTOT  352       // KAV + KP
#define NCB   391       // ceil(49999/128) logits col-blocks
#define SHIFT 20.0f

typedef __attribute__((ext_vector_type(8))) short short8;
typedef __attribute__((ext_vector_type(4))) short short4_t;
typedef __attribute__((ext_vector_type(4))) float f32x4;
typedef unsigned short ushort_t;

__device__ __forceinline__ float sigm(float x) { return 1.0f / (1.0f + __expf(-x)); }
__device__ __forceinline__ float mytanh(float x) {
  x = fminf(15.0f, fmaxf(-15.0f, x));
  float e = __expf(-2.0f * x);
  return (1.0f - e) / (1.0f + e);
}
__device__ __forceinline__ float f4c(const float4& v, int k) { return ((const float*)&v)[k]; }
__device__ __forceinline__ ushort_t f2bf(float f) {  // RNE float->bf16
  union { float f; unsigned u; } v; v.f = f;
  unsigned r = v.u + 0x7FFF + ((v.u >> 16) & 1);
  return (ushort_t)(r >> 16);
}
__device__ __forceinline__ float bf2f(ushort_t s) {
  union { unsigned u; float f; } v; v.u = ((unsigned)s) << 16;
  return v.f;
}
__device__ __forceinline__ short8 cvt8(const float* __restrict__ p) {
  float4 v0 = *(const float4*)p, v1 = *(const float4*)(p + 4);
  short8 r;
  r[0] = (short)f2bf(v0.x); r[1] = (short)f2bf(v0.y);
  r[2] = (short)f2bf(v0.z); r[3] = (short)f2bf(v0.w);
  r[4] = (short)f2bf(v1.x); r[5] = (short)f2bf(v1.y);
  r[6] = (short)f2bf(v1.z); r[7] = (short)f2bf(v1.w);
  return r;
}

// ---------------------------------------------------------------------------
// C0: emb (fp32 [50000][100]) -> eb2 (bf16 [50000][128], zero-padded cols)
// ---------------------------------------------------------------------------
__global__ __launch_bounds__(256) void k_cvt_emb2(
    const float* __restrict__ emb, ushort_t* __restrict__ eb2)
{
  const int tid = blockIdx.x * 256 + threadIdx.x;
  const int r = tid >> 5, c4 = (tid & 31) * 4;
  if (r >= NNODES) return;
  short4_t o = {0, 0, 0, 0};
  if (c4 < DD) {
    float4 v = *(const float4*)(emb + (size_t)r * DD + c4);
    o.x = (short)f2bf(f4c(v, 0)); o.y = (short)f2bf(f4c(v, 1));
    o.z = (short)f2bf(f4c(v, 2)); o.w = (short)f2bf(f4c(v, 3));
  }
  *(short4_t*)(eb2 + (size_t)r * KP + c4) = o;
}

// ---------------------------------------------------------------------------
// C1: weights -> transposed zero-padded bf16 (same as R2).
// ---------------------------------------------------------------------------
__global__ __launch_bounds__(256) void k_cvt_w(
    const float* __restrict__ Wi, const float* __restrict__ Wo,
    const float* __restrict__ gk, const float* __restrict__ ck,
    ushort_t* __restrict__ WioT, ushort_t* __restrict__ gkT,
    ushort_t* __restrict__ ckT)
{
  const int idx = blockIdx.x * 256 + threadIdx.x;
  const int y = blockIdx.y;
  if (y == 0) {
    if (idx >= 208 * 128) return;
    int n = idx >> 7, k = idx & 127;
    float v = 0.0f;
    if (k < DD) {
      if (n < 100) v = Wi[k * DD + n];
      else if (n < 200) v = Wo[k * DD + (n - 100)];
    }
    WioT[idx] = f2bf(v);
  } else if (y == 1) {
    if (idx >= 208 * KTOT) return;
    int n = idx / KTOT, k = idx - n * KTOT;
    float v = 0.0f;
    if (n < 200) {
      if (k < KAV) { if (k < 200) v = gk[k * 200 + n]; }
      else { int kk = k - KAV; if (kk < 100) v = gk[(200 + kk) * 200 + n]; }
    }
    gkT[idx] = f2bf(v);
  } else {
    if (idx >= 112 * KTOT) return;
    int n = idx / KTOT, k = idx - n * KTOT;
    float v = 0.0f;
    if (n < 100) {
      if (k < KAV) { if (k < 200) v = ck[k * DD + n]; }
      else { int kk = k - KAV; if (kk < 100) v = ck[(200 + kk) * DD + n]; }
    }
    ckT[idx] = f2bf(v);
  }
}

// ---------------------------------------------------------------------------
// K1: fused fio + av per batch. Block = batch b (64 rows, 4 waves).
// Phase 1: fi/fo = gather(eb2,item)@[Wi|Wo]+bias -> LDS s_f[2][112][72] bf16.
// Phase 2: av = [adj_in@fi | adj_out@fo] (adj converted in-register) -> avb.
// ---------------------------------------------------------------------------
__global__ __launch_bounds__(256) void k_fio_av(
    const ushort_t* __restrict__ eb2, const int* __restrict__ item,
    const ushort_t* __restrict__ WioT,
    const float* __restrict__ bi, const float* __restrict__ bo,
    const float* __restrict__ adj_in, const float* __restrict__ adj_out,
    ushort_t* __restrict__ avb)
{
  __shared__ ushort_t s_f[2][112][72];   // [fi|fo][avcol][node], +8 pad
  const int t = threadIdx.x, wave = t >> 6, lane = t & 63;
  const int n16 = lane & 15, quad = lane >> 4;
  const int b = blockIdx.x;
  const int m0 = b * 64 + wave * 16;

  // zero pad rows 100..111 (multiplied into discarded av cols, but keep clean)
  for (int idx = t; idx < 2 * 12 * 64; idx += 256) {
    int which = idx / 768, rem = idx - which * 768;
    s_f[which][100 + rem / 64][rem & 63] = 0;
  }

  // ---- Phase 1: fio ----
  const ushort_t* arow = eb2 + (size_t)item[m0 + n16] * KP + quad * 8;
  short8 af[4];
#pragma unroll
  for (int ks = 0; ks < 4; ++ks) af[ks] = *(const short8*)(arow + ks * 32);

  const int node0 = wave * 16 + quad * 4;
#pragma unroll
  for (int sub = 0; sub < 13; ++sub) {
    const ushort_t* brow = WioT + (size_t)(sub * 16 + n16) * KP + quad * 8;
    f32x4 acc = {0.0f, 0.0f, 0.0f, 0.0f};
#pragma unroll
    for (int ks = 0; ks < 4; ++ks)
      acc = __builtin_amdgcn_mfma_f32_16x16x32_bf16(af[ks], *(const short8*)(brow + ks * 32), acc, 0, 0, 0);
    const int col = sub * 16 + n16;
    if (col < 200) {
      const float bias = (col < 100) ? bi[col] : bo[col - 100];
      short4_t st;
#pragma unroll
      for (int r = 0; r < 4; ++r) ((ushort_t*)&st)[r] = f2bf(acc[r] + bias);
      const int which = (col < 100) ? 0 : 1;
      const int c = (col < 100) ? col : col - 100;
      *(short4_t*)&s_f[which][c][node0] = st;
    }
  }
  __syncthreads();

  // ---- Phase 2: av ----
  const float* aI = adj_in  + ((size_t)b * 64 + wave * 16 + n16) * 64 + quad * 8;
  const float* aO = adj_out + ((size_t)b * 64 + wave * 16 + n16) * 64 + quad * 8;
  short8 afI[2], afO[2];
#pragma unroll
  for (int ks = 0; ks < 2; ++ks) {
    afI[ks] = cvt8(aI + ks * 32);
    afO[ks] = cvt8(aO + ks * 32);
  }
#pragma unroll
  for (int sub = 0; sub < 7; ++sub) {
    const int col = sub * 16 + n16;
    const ushort_t* bI = &s_f[0][col][quad * 8];
    const ushort_t* bO = &s_f[1][col][quad * 8];
    f32x4 accI = {0, 0, 0, 0}, accO = {0, 0, 0, 0};
#pragma unroll
    for (int ks = 0; ks < 2; ++ks) {
      accI = __builtin_amdgcn_mfma_f32_16x16x32_bf16(afI[ks], *(const short8*)(bI + ks * 32), accI, 0, 0, 0);
      accO = __builtin_amdgcn_mfma_f32_16x16x32_bf16(afO[ks], *(const short8*)(bO + ks * 32), accO, 0, 0, 0);
    }
    if (col < 100) {
#pragma unroll
      for (int r = 0; r < 4; ++r) {
        const size_t row = (size_t)b * 64 + wave * 16 + quad * 4 + r;
        avb[row * KAV + col] = f2bf(accI[r]);
        avb[row * KAV + 100 + col] = f2bf(accO[r]);
      }
    }
  }
}

// ---------------------------------------------------------------------------
// K2: fused GRU via MFMA (padded LDS rows: 136 shorts, conflict-free b128).
// ---------------------------------------------------------------------------
__global__ __launch_bounds__(256) void k_gru_mfma(
    const ushort_t* __restrict__ avb, const ushort_t* __restrict__ eb2,
    const int* __restrict__ item,
    const ushort_t* __restrict__ gkT, const float* __restrict__ gb,
    const ushort_t* __restrict__ ckT, const float* __restrict__ cbs,
    float* __restrict__ fin2)
{
  __shared__ ushort_t s_h[4][16][136];
  __shared__ ushort_t s_rh[4][16][136];
  __shared__ float    s_u[4][16][104];
  const int t = threadIdx.x, wave = t >> 6, lane = t & 63;
  const int n16 = lane & 15, quad = lane >> 4;
  const int m0 = (blockIdx.x * 4 + wave) * 16;

  // stage h rows into LDS (bf16) + zero rh pad cols 100..127
  {
    const int row_s = lane & 15, chunk = lane >> 4;
    const ushort_t* hsrc = eb2 + (size_t)item[m0 + row_s] * KP + chunk * 32;
#pragma unroll
    for (int j = 0; j < 4; ++j)
      *(short8*)&s_h[wave][row_s][chunk * 32 + j * 8] = *(const short8*)(hsrc + j * 8);
#pragma unroll
    for (int j = 0; j < 7; ++j)
      s_rh[wave][row_s][100 + chunk * 7 + j] = 0;
  }

  const ushort_t* avrow = avb + (size_t)(m0 + n16) * KAV + quad * 8;
  short8 afa[7];
#pragma unroll
  for (int ks = 0; ks < 7; ++ks) afa[ks] = *(const short8*)(avrow + ks * 32);
  const ushort_t* hrow = eb2 + (size_t)item[m0 + n16] * KP + quad * 8;
  short8 afh[4];
#pragma unroll
  for (int ks = 0; ks < 4; ++ks) afh[ks] = *(const short8*)(hrow + ks * 32);
  __syncthreads();

  // Phase 1: gates
#pragma unroll
  for (int sub = 0; sub < 13; ++sub) {
    const ushort_t* brow = gkT + (size_t)(sub * 16 + n16) * KTOT + quad * 8;
    f32x4 acc = {0, 0, 0, 0};
#pragma unroll
    for (int ks = 0; ks < 7; ++ks)
      acc = __builtin_amdgcn_mfma_f32_16x16x32_bf16(afa[ks], *(const short8*)(brow + ks * 32), acc, 0, 0, 0);
#pragma unroll
    for (int ks = 0; ks < 4; ++ks)
      acc = __builtin_amdgcn_mfma_f32_16x16x32_bf16(afh[ks], *(const short8*)(brow + KAV + ks * 32), acc, 0, 0, 0);
    const int col = sub * 16 + n16;
    if (col < 200) {
      const float bias = gb[col];
#pragma unroll
      for (int r = 0; r < 4; ++r) {
        const int row = quad * 4 + r;
        const float g = sigm(acc[r] + bias);
        if (col < 100) {
          s_rh[wave][row][col] = f2bf(g * bf2f(s_h[wave][row][col]));
        } else {
          s_u[wave][row][col - 100] = g;
        }
      }
    }
  }
  __syncthreads();

  // Phase 2: candidate + output
  short8 afr[4];
#pragma unroll
  for (int ks = 0; ks < 4; ++ks) afr[ks] = *(const short8*)&s_rh[wave][n16][ks * 32];
#pragma unroll
  for (int sub = 0; sub < 7; ++sub) {
    const ushort_t* brow = ckT + (size_t)(sub * 16 + n16) * KTOT + quad * 8;
    f32x4 acc = {0, 0, 0, 0};
#pragma unroll
    for (int ks = 0; ks < 7; ++ks)
      acc = __builtin_amdgcn_mfma_f32_16x16x32_bf16(afa[ks], *(const short8*)(brow + ks * 32), acc, 0, 0, 0);
#pragma unroll
    for (int ks = 0; ks < 4; ++ks)
      acc = __builtin_amdgcn_mfma_f32_16x16x32_bf16(afr[ks], *(const short8*)(brow + KAV + ks * 32), acc, 0, 0, 0);
    const int col = sub * 16 + n16;
    if (col < 100) {
      const float bias = cbs[col];
#pragma unroll
      for (int r = 0; r < 4; ++r) {
        const int row = quad * 4 + r;
        const float c = mytanh(acc[r] + bias);
        const float u = s_u[wave][row][col];
        const float hv = bf2f(s_h[wave][row][col]);
        fin2[(size_t)(m0 + row) * DD + col] = u * hv + (1.0f - u) * c;
      }
    }
  }
}

// ---------------------------------------------------------------------------
// K3: attention readout -> mab[b][128] bf16 (zero-padded k>=100)
// Round-4 rewrite: serial phases parallelized —
//   - mask-sum via wave-0 shuffle reduce (was: 64-iter loop on thread 0)
//   - seq_h gather via float4 (was: scalar)
//   - last_h staged to LDS, w1 dot unrolled (was: 100 serial scalar global)
//   - coef/nv dot via float4 LDS reads
// Math unchanged (fp32 throughout).
// ---------------------------------------------------------------------------
__global__ __launch_bounds__(256) void k_attn(
    const float* __restrict__ fin2, const int* __restrict__ alias_,
    const float* __restrict__ mask,
    const float* __restrict__ w1, const float* __restrict__ w2,
    const float* __restrict__ nv, const float* __restrict__ nb,
    ushort_t* __restrict__ mab)
{
  __shared__ float s_seqh[NNODE * DD];
  __shared__ float s_m[NNODE * DD];
  __shared__ float s_last[104];
  __shared__ float s_lh[104];
  __shared__ float s_coef[NNODE];
  __shared__ int s_lastid;
  const int b = blockIdx.x, t = threadIdx.x;

  // phase 1: lastid via wave-parallel mask sum (wave 0)
  if (t < 64) {
    float v = mask[b * LLEN + t];
    v += __shfl_xor(v, 1, 64);
    v += __shfl_xor(v, 2, 64);
    v += __shfl_xor(v, 4, 64);
    v += __shfl_xor(v, 8, 64);
    v += __shfl_xor(v, 16, 64);
    v += __shfl_xor(v, 32, 64);
    if (t == 0) {
      int rm = (int)(v + 0.5f);
      s_lastid = alias_[b * LLEN + rm - 1];
    }
  }
  // phase 2: gather seq_h rows (float4; DD=100 = 25 float4 per row)
  for (int i4 = t; i4 < NNODE * 25; i4 += 256) {
    int l = i4 / 25, d4 = (i4 - l * 25) * 4;
    int n = alias_[b * LLEN + l];
    *(float4*)&s_seqh[l * DD + d4] = *(const float4*)(fin2 + ((size_t)b * NNODE + n) * DD + d4);
  }
  __syncthreads();

  // phase 2b: stage last_h row to LDS
  if (t < 25) {
    *(float4*)&s_lh[t * 4] = *(const float4*)(fin2 + ((size_t)b * NNODE + s_lastid) * DD + t * 4);
  }
  __syncthreads();

  // phase 3: s_last[e] = last_h @ w1 (w1[k][e], coalesced across e)
  if (t < DD) {
    float acc = 0.0f;
#pragma unroll 4
    for (int k = 0; k < DD; ++k) acc += s_lh[k] * w1[k * DD + t];
    s_last[t] = acc;
  }
  __syncthreads();

  // phase 4: s_m = sigm(seq_h @ w2 + last + nb)
  {
    const int tx = t & 31, ty = t >> 5, cb4 = tx * 4;
    if (cb4 < DD) {
      float acc[8][4] = {};
      for (int k4 = 0; k4 < 25; ++k4) {
        float4 bv[4];
#pragma unroll
        for (int kk = 0; kk < 4; ++kk) bv[kk] = *(const float4*)(w2 + (size_t)(k4 * 4 + kk) * DD + cb4);
#pragma unroll
        for (int i = 0; i < 8; ++i) {
          float4 a = *(const float4*)(&s_seqh[(ty * 8 + i) * DD + k4 * 4]);
#pragma unroll
          for (int kk = 0; kk < 4; ++kk) {
            float av_ = f4c(a, kk);
#pragma unroll
            for (int j = 0; j < 4; ++j) acc[i][j] += av_ * f4c(bv[kk], j);
          }
        }
      }
#pragma unroll
      for (int i = 0; i < 8; ++i) {
        int l = ty * 8 + i;
#pragma unroll
        for (int j = 0; j < 4; ++j) {
          int e = cb4 + j;
          s_m[l * DD + e] = sigm(acc[i][j] + s_last[e] + nb[e]);
        }
      }
    }
  }
  __syncthreads();

  // phase 5: coef[l] = (m[l] . nv) * mask[l]  (float4)
  if (t < LLEN) {
    float acc = 0.0f;
#pragma unroll 5
    for (int e4 = 0; e4 < 25; ++e4) {
      float4 m4 = *(const float4*)&s_m[t * DD + e4 * 4];
      float4 v4 = *(const float4*)(nv + e4 * 4);
      acc += m4.x * v4.x + m4.y * v4.y + m4.z * v4.z + m4.w * v4.w;
    }
    s_coef[t] = acc * mask[b * LLEN + t];
  }
  __syncthreads();

  // phase 6: ma[d] = sum_l coef[l] * seq_h[l][d]
  if (t < DD) {
    float acc = 0.0f;
#pragma unroll 4
    for (int l = 0; l < LLEN; ++l) acc += s_coef[l] * s_seqh[l * DD + t];
    mab[(size_t)b * KP + t] = f2bf(acc);
  } else if (t < KP) {
    mab[(size_t)b * KP + t] = 0;
  }
}

// ---------------------------------------------------------------------------
// K4: logits = mab @ eb2[1:]^T via MFMA.
//
// Round-4: keep round-2's LDS-transposed coalesced store format (512/256-B
// row runs — round 3 proved per-fragment scatter stores cost 2x), but:
//  (1) the C tile is written/read per-wave only -> the __syncthreads was
//      never needed; removed.
//  (2) half-tile split: s_o[4][16][68] (64 cols per pass, 2 passes) halves
//      LDS 33.8 -> 17.4 KB => 8 blocks/CU = 32 waves (~100% occupancy) to
//      attack the measured latency-bound 16%-issue regime.
// Store: NT float4, per-iter 4 rows x 256 B runs. XCD-ownership swizzle
// retained (FETCH 50 -> 6.8 MB in round 2).
// ---------------------------------------------------------------------------
__global__ __launch_bounds__(256) void k_logits_mfma(
    const ushort_t* __restrict__ eb2, const ushort_t* __restrict__ mab,
    float* __restrict__ out, float* __restrict__ sump)
{
  __shared__ float s_o[4][16][68];   // per-wave 16x64 half C tile, +4 pad
  const int t = threadIdx.x;
  const int wave = t >> 6, lane = t & 63;
  const int n16 = lane & 15, quad = lane >> 4;
  const int bid = blockIdx.x;
  const int xcd = bid & 7;
  const int j = bid >> 3;                 // 0..391
  const int stripe = j & 7;
  const int grp = j >> 3;
  const int cblk = xcd * 49 + grp;        // contiguous 49-cblk chunk per XCD
  if (cblk >= NCB) return;                // 8 tail blocks (xcd=7, grp=48)
  const int m0 = stripe * 64 + wave * 16;

  short8 afr[4];
  const ushort_t* abase = mab + (size_t)(m0 + n16) * KP + quad * 8;
#pragma unroll
  for (int ks = 0; ks < 4; ++ks) afr[ks] = *(const short8*)(abase + ks * 32);

  float* lg = out + 1;
  float s[4] = {0.0f, 0.0f, 0.0f, 0.0f};

#pragma unroll
  for (int half = 0; half < 2; ++half) {
#pragma unroll
    for (int ss = 0; ss < 4; ++ss) {
      const int sub = half * 4 + ss;
      const int c = cblk * 128 + sub * 16 + n16;
      const ushort_t* bbase = eb2 + (size_t)((c < NM1) ? (c + 1) : 0) * KP + quad * 8;
      f32x4 acc = {0.0f, 0.0f, 0.0f, 0.0f};
#pragma unroll
      for (int ks = 0; ks < 4; ++ks) {
        short8 bfr = *(const short8*)(bbase + ks * 32);
        acc = __builtin_amdgcn_mfma_f32_16x16x32_bf16(afr[ks], bfr, acc, 0, 0, 0);
      }
#pragma unroll
      for (int r = 0; r < 4; ++r) {
        s_o[wave][quad * 4 + r][ss * 16 + n16] = acc[r];
        if (c < NM1) s[r] += __expf(acc[r] - SHIFT);
      }
    }
    // store this half: per iter 4 rows x 256 B contiguous runs
#pragma unroll
    for (int it = 0; it < 4; ++it) {
      const int row = it * 4 + quad;
      const size_t gr = m0 + row;
      f32x4 v = *(const f32x4*)&s_o[wave][row][n16 * 4];
      const int c0 = cblk * 128 + half * 64 + n16 * 4;
      if (c0 + 3 < NM1) {
        __builtin_nontemporal_store(v, (f32x4*)(lg + gr * NM1 + c0));
      } else {
#pragma unroll
        for (int e = 0; e < 4; ++e)
          if (c0 + e < NM1)
            __builtin_nontemporal_store(v[e], lg + gr * NM1 + c0 + e);
      }
    }
  }

  const int row0 = m0 + quad * 4;
#pragma unroll
  for (int r = 0; r < 4; ++r) {
    float x = s[r];
    x += __shfl_xor(x, 1, 64);
    x += __shfl_xor(x, 2, 64);
    x += __shfl_xor(x, 4, 64);
    x += __shfl_xor(x, 8, 64);
    if (n16 == 0) sump[(size_t)(row0 + r) * NCB + cblk] = x;
  }
}

// ---------------------------------------------------------------------------
// K5: rowterm[r] = logits[r][tar[r]-1] - (log(sum) + SHIFT)
// ---------------------------------------------------------------------------
__global__ __launch_bounds__(64) void k_lse(
    const float* __restrict__ sump, const float* __restrict__ out,
    const int* __restrict__ tar, float* __restrict__ rowterm)
{
  const int r = blockIdx.x, t = threadIdx.x;
  float s = 0.0f;
  for (int i = t; i < NCB; i += 64) s += sump[(size_t)r * NCB + i];
  for (int m = 1; m < 64; m <<= 1) s += __shfl_xor(s, m, 64);
  if (t == 0) {
    int label = tar[r] - 1;
    const float* lg = out + 1;
    rowterm[r] = lg[(size_t)r * NM1 + label] - (logf(s) + SHIFT);
  }
}

// ---------------------------------------------------------------------------
// K6: loss = -mean(rowterm)
// ---------------------------------------------------------------------------
__global__ __launch_bounds__(256) void k_loss(
    const float* __restrict__ rowterm, float* __restrict__ out)
{
  const int t = threadIdx.x;
  __shared__ float red[4];
  float s = rowterm[t] + rowterm[t + 256];
  for (int m = 1; m < 64; m <<= 1) s += __shfl_xor(s, m, 64);
  if ((t & 63) == 0) red[t >> 6] = s;
  __syncthreads();
  if (t == 0) out[0] = -(red[0] + red[1] + red[2] + red[3]) / (float)BB;
}

// ---------------------------------------------------------------------------
extern "C" void kernel_launch(void* const* d_in, const int* in_sizes, int n_in,
                              void* d_out, int out_size, void* d_ws, size_t ws_size,
                              hipStream_t stream)
{
  (void)in_sizes; (void)n_in; (void)out_size; (void)ws_size;
  const float* adj_in  = (const float*)d_in[0];
  const float* adj_out = (const float*)d_in[1];
  const int*   item    = (const int*)d_in[2];
  const int*   alias_  = (const int*)d_in[3];
  const float* mask    = (const float*)d_in[4];
  const int*   tar     = (const int*)d_in[5];
  const float* emb     = (const float*)d_in[6];
  const float* W_in    = (const float*)d_in[7];
  const float* b_in    = (const float*)d_in[8];
  const float* W_out   = (const float*)d_in[9];
  const float* b_out   = (const float*)d_in[10];
  const float* gk      = (const float*)d_in[11];
  const float* gb      = (const float*)d_in[12];
  const float* ck      = (const float*)d_in[13];
  const float* cbs     = (const float*)d_in[14];
  const float* w1      = (const float*)d_in[15];
  const float* w2      = (const float*)d_in[16];
  const float* nv      = (const float*)d_in[17];
  const float* nb      = (const float*)d_in[18];
  float* out = (float*)d_out;

  // Workspace layout, ushort units.
  ushort_t* usw = (ushort_t*)d_ws;
  ushort_t* eb2  = usw;                    // 50000*128     = 6,400,000
  ushort_t* avb  = usw + 6400000;          // 32768*224     = 7,340,032
  ushort_t* WioT = usw + 13740032;         // 208*128       = 26,624
  ushort_t* gkT  = usw + 13766656;         // 208*352       = 73,216
  ushort_t* ckT  = usw + 13839872;         // 112*352       = 39,424
  ushort_t* mab  = usw + 13879296;         // 512*128       = 65,536
  float* fpool   = (float*)(usw + 13944832);
  float* fin2    = fpool;                  // 32768*100     = 3,276,800
  float* sump    = fpool + 3276800;        // 512*391       = 200,192
  float* rowterm = fpool + 3276800 + 200192;   // 512

  k_cvt_emb2<<<dim3(6250), 256, 0, stream>>>(emb, eb2);
  k_cvt_w   <<<dim3(287, 3), 256, 0, stream>>>(W_in, W_out, gk, ck, WioT, gkT, ckT);
  k_fio_av  <<<dim3(512), 256, 0, stream>>>(eb2, item, WioT, b_in, b_out, adj_in, adj_out, avb);
  k_gru_mfma<<<dim3(512), 256, 0, stream>>>(avb, eb2, item, gkT, gb, ckT, cbs, fin2);
  k_attn    <<<dim3(512), 256, 0, stream>>>(fin2, alias_, mask, w1, w2, nv, nb, mab);
  k_logits_mfma<<<dim3(3136), 256, 0, stream>>>(eb2, mab, out, sump);
  k_lse     <<<dim3(512), 64, 0, stream>>>(sump, out, tar, rowterm);
  k_loss    <<<dim3(1), 256, 0, stream>>>(rowterm, out);
}

// Round 5
// 301.428 us; speedup vs baseline: 1.2147x; 1.0807x over previous
//
#include <hip/hip_runtime.h>
#include <math.h>

// Problem constants
#define BB    512
#define NNODE 64
#define LLEN  64
#define DD    100
#define NNODES 50000
#define NM1   49999     // n_nodes - 1
#define KP    128       // padded K for emb/h (4 k-steps of 32)
#define KAV   224       // padded K for av section (7 k-steps)
#define KTOT  352       // KAV + KP
#define NCB   391       // ceil(49999/128) logits col-blocks
#define SHIFT 20.0f

typedef __attribute__((ext_vector_type(8))) short short8;
typedef __attribute__((ext_vector_type(4))) short short4_t;
typedef __attribute__((ext_vector_type(4))) float f32x4;
typedef unsigned short ushort_t;

__device__ __forceinline__ float sigm(float x) { return 1.0f / (1.0f + __expf(-x)); }
__device__ __forceinline__ float mytanh(float x) {
  x = fminf(15.0f, fmaxf(-15.0f, x));
  float e = __expf(-2.0f * x);
  return (1.0f - e) / (1.0f + e);
}
__device__ __forceinline__ float f4c(const float4& v, int k) { return ((const float*)&v)[k]; }
__device__ __forceinline__ ushort_t f2bf(float f) {  // RNE float->bf16
  union { float f; unsigned u; } v; v.f = f;
  unsigned r = v.u + 0x7FFF + ((v.u >> 16) & 1);
  return (ushort_t)(r >> 16);
}
__device__ __forceinline__ float bf2f(ushort_t s) {
  union { unsigned u; float f; } v; v.u = ((unsigned)s) << 16;
  return v.f;
}
__device__ __forceinline__ short8 cvt8(const float* __restrict__ p) {
  float4 v0 = *(const float4*)p, v1 = *(const float4*)(p + 4);
  short8 r;
  r[0] = (short)f2bf(v0.x); r[1] = (short)f2bf(v0.y);
  r[2] = (short)f2bf(v0.z); r[3] = (short)f2bf(v0.w);
  r[4] = (short)f2bf(v1.x); r[5] = (short)f2bf(v1.y);
  r[6] = (short)f2bf(v1.z); r[7] = (short)f2bf(v1.w);
  return r;
}

// ---------------------------------------------------------------------------
// C0: emb (fp32 [50000][100]) -> eb2 (bf16 [50000][128], zero-padded cols)
// ---------------------------------------------------------------------------
__global__ __launch_bounds__(256) void k_cvt_emb2(
    const float* __restrict__ emb, ushort_t* __restrict__ eb2)
{
  const int tid = blockIdx.x * 256 + threadIdx.x;
  const int r = tid >> 5, c4 = (tid & 31) * 4;
  if (r >= NNODES) return;
  short4_t o = {0, 0, 0, 0};
  if (c4 < DD) {
    float4 v = *(const float4*)(emb + (size_t)r * DD + c4);
    o.x = (short)f2bf(f4c(v, 0)); o.y = (short)f2bf(f4c(v, 1));
    o.z = (short)f2bf(f4c(v, 2)); o.w = (short)f2bf(f4c(v, 3));
  }
  *(short4_t*)(eb2 + (size_t)r * KP + c4) = o;
}

// ---------------------------------------------------------------------------
// C1: weights -> transposed zero-padded bf16 (same as R2).
// ---------------------------------------------------------------------------
__global__ __launch_bounds__(256) void k_cvt_w(
    const float* __restrict__ Wi, const float* __restrict__ Wo,
    const float* __restrict__ gk, const float* __restrict__ ck,
    ushort_t* __restrict__ WioT, ushort_t* __restrict__ gkT,
    ushort_t* __restrict__ ckT)
{
  const int idx = blockIdx.x * 256 + threadIdx.x;
  const int y = blockIdx.y;
  if (y == 0) {
    if (idx >= 208 * 128) return;
    int n = idx >> 7, k = idx & 127;
    float v = 0.0f;
    if (k < DD) {
      if (n < 100) v = Wi[k * DD + n];
      else if (n < 200) v = Wo[k * DD + (n - 100)];
    }
    WioT[idx] = f2bf(v);
  } else if (y == 1) {
    if (idx >= 208 * KTOT) return;
    int n = idx / KTOT, k = idx - n * KTOT;
    float v = 0.0f;
    if (n < 200) {
      if (k < KAV) { if (k < 200) v = gk[k * 200 + n]; }
      else { int kk = k - KAV; if (kk < 100) v = gk[(200 + kk) * 200 + n]; }
    }
    gkT[idx] = f2bf(v);
  } else {
    if (idx >= 112 * KTOT) return;
    int n = idx / KTOT, k = idx - n * KTOT;
    float v = 0.0f;
    if (n < 100) {
      if (k < KAV) { if (k < 200) v = ck[k * DD + n]; }
      else { int kk = k - KAV; if (kk < 100) v = ck[(200 + kk) * DD + n]; }
    }
    ckT[idx] = f2bf(v);
  }
}

// ---------------------------------------------------------------------------
// K1: fused fio + av per batch. Block = batch b (64 rows, 4 waves).
// Phase 1: fi/fo = gather(eb2,item)@[Wi|Wo]+bias -> LDS s_f[2][112][72] bf16.
// Phase 2: av = [adj_in@fi | adj_out@fo] (adj converted in-register) -> avb.
// ---------------------------------------------------------------------------
__global__ __launch_bounds__(256) void k_fio_av(
    const ushort_t* __restrict__ eb2, const int* __restrict__ item,
    const ushort_t* __restrict__ WioT,
    const float* __restrict__ bi, const float* __restrict__ bo,
    const float* __restrict__ adj_in, const float* __restrict__ adj_out,
    ushort_t* __restrict__ avb)
{
  __shared__ ushort_t s_f[2][112][72];   // [fi|fo][avcol][node], +8 pad
  const int t = threadIdx.x, wave = t >> 6, lane = t & 63;
  const int n16 = lane & 15, quad = lane >> 4;
  const int b = blockIdx.x;
  const int m0 = b * 64 + wave * 16;

  // zero pad rows 100..111 (multiplied into discarded av cols, but keep clean)
  for (int idx = t; idx < 2 * 12 * 64; idx += 256) {
    int which = idx / 768, rem = idx - which * 768;
    s_f[which][100 + rem / 64][rem & 63] = 0;
  }

  // ---- Phase 1: fio ----
  const ushort_t* arow = eb2 + (size_t)item[m0 + n16] * KP + quad * 8;
  short8 af[4];
#pragma unroll
  for (int ks = 0; ks < 4; ++ks) af[ks] = *(const short8*)(arow + ks * 32);

  const int node0 = wave * 16 + quad * 4;
#pragma unroll
  for (int sub = 0; sub < 13; ++sub) {
    const ushort_t* brow = WioT + (size_t)(sub * 16 + n16) * KP + quad * 8;
    f32x4 acc = {0.0f, 0.0f, 0.0f, 0.0f};
#pragma unroll
    for (int ks = 0; ks < 4; ++ks)
      acc = __builtin_amdgcn_mfma_f32_16x16x32_bf16(af[ks], *(const short8*)(brow + ks * 32), acc, 0, 0, 0);
    const int col = sub * 16 + n16;
    if (col < 200) {
      const float bias = (col < 100) ? bi[col] : bo[col - 100];
      short4_t st;
#pragma unroll
      for (int r = 0; r < 4; ++r) ((ushort_t*)&st)[r] = f2bf(acc[r] + bias);
      const int which = (col < 100) ? 0 : 1;
      const int c = (col < 100) ? col : col - 100;
      *(short4_t*)&s_f[which][c][node0] = st;
    }
  }
  __syncthreads();

  // ---- Phase 2: av ----
  const float* aI = adj_in  + ((size_t)b * 64 + wave * 16 + n16) * 64 + quad * 8;
  const float* aO = adj_out + ((size_t)b * 64 + wave * 16 + n16) * 64 + quad * 8;
  short8 afI[2], afO[2];
#pragma unroll
  for (int ks = 0; ks < 2; ++ks) {
    afI[ks] = cvt8(aI + ks * 32);
    afO[ks] = cvt8(aO + ks * 32);
  }
#pragma unroll
  for (int sub = 0; sub < 7; ++sub) {
    const int col = sub * 16 + n16;
    const ushort_t* bI = &s_f[0][col][quad * 8];
    const ushort_t* bO = &s_f[1][col][quad * 8];
    f32x4 accI = {0, 0, 0, 0}, accO = {0, 0, 0, 0};
#pragma unroll
    for (int ks = 0; ks < 2; ++ks) {
      accI = __builtin_amdgcn_mfma_f32_16x16x32_bf16(afI[ks], *(const short8*)(bI + ks * 32), accI, 0, 0, 0);
      accO = __builtin_amdgcn_mfma_f32_16x16x32_bf16(afO[ks], *(const short8*)(bO + ks * 32), accO, 0, 0, 0);
    }
    if (col < 100) {
#pragma unroll
      for (int r = 0; r < 4; ++r) {
        const size_t row = (size_t)b * 64 + wave * 16 + quad * 4 + r;
        avb[row * KAV + col] = f2bf(accI[r]);
        avb[row * KAV + 100 + col] = f2bf(accO[r]);
      }
    }
  }
}

// ---------------------------------------------------------------------------
// K2: fused GRU via MFMA (padded LDS rows: 136 shorts, conflict-free b128).
// ---------------------------------------------------------------------------
__global__ __launch_bounds__(256) void k_gru_mfma(
    const ushort_t* __restrict__ avb, const ushort_t* __restrict__ eb2,
    const int* __restrict__ item,
    const ushort_t* __restrict__ gkT, const float* __restrict__ gb,
    const ushort_t* __restrict__ ckT, const float* __restrict__ cbs,
    float* __restrict__ fin2)
{
  __shared__ ushort_t s_h[4][16][136];
  __shared__ ushort_t s_rh[4][16][136];
  __shared__ float    s_u[4][16][104];
  const int t = threadIdx.x, wave = t >> 6, lane = t & 63;
  const int n16 = lane & 15, quad = lane >> 4;
  const int m0 = (blockIdx.x * 4 + wave) * 16;

  // stage h rows into LDS (bf16) + zero rh pad cols 100..127
  {
    const int row_s = lane & 15, chunk = lane >> 4;
    const ushort_t* hsrc = eb2 + (size_t)item[m0 + row_s] * KP + chunk * 32;
#pragma unroll
    for (int j = 0; j < 4; ++j)
      *(short8*)&s_h[wave][row_s][chunk * 32 + j * 8] = *(const short8*)(hsrc + j * 8);
#pragma unroll
    for (int j = 0; j < 7; ++j)
      s_rh[wave][row_s][100 + chunk * 7 + j] = 0;
  }

  const ushort_t* avrow = avb + (size_t)(m0 + n16) * KAV + quad * 8;
  short8 afa[7];
#pragma unroll
  for (int ks = 0; ks < 7; ++ks) afa[ks] = *(const short8*)(avrow + ks * 32);
  const ushort_t* hrow = eb2 + (size_t)item[m0 + n16] * KP + quad * 8;
  short8 afh[4];
#pragma unroll
  for (int ks = 0; ks < 4; ++ks) afh[ks] = *(const short8*)(hrow + ks * 32);
  __syncthreads();

  // Phase 1: gates
#pragma unroll
  for (int sub = 0; sub < 13; ++sub) {
    const ushort_t* brow = gkT + (size_t)(sub * 16 + n16) * KTOT + quad * 8;
    f32x4 acc = {0, 0, 0, 0};
#pragma unroll
    for (int ks = 0; ks < 7; ++ks)
      acc = __builtin_amdgcn_mfma_f32_16x16x32_bf16(afa[ks], *(const short8*)(brow + ks * 32), acc, 0, 0, 0);
#pragma unroll
    for (int ks = 0; ks < 4; ++ks)
      acc = __builtin_amdgcn_mfma_f32_16x16x32_bf16(afh[ks], *(const short8*)(brow + KAV + ks * 32), acc, 0, 0, 0);
    const int col = sub * 16 + n16;
    if (col < 200) {
      const float bias = gb[col];
#pragma unroll
      for (int r = 0; r < 4; ++r) {
        const int row = quad * 4 + r;
        const float g = sigm(acc[r] + bias);
        if (col < 100) {
          s_rh[wave][row][col] = f2bf(g * bf2f(s_h[wave][row][col]));
        } else {
          s_u[wave][row][col - 100] = g;
        }
      }
    }
  }
  __syncthreads();

  // Phase 2: candidate + output
  short8 afr[4];
#pragma unroll
  for (int ks = 0; ks < 4; ++ks) afr[ks] = *(const short8*)&s_rh[wave][n16][ks * 32];
#pragma unroll
  for (int sub = 0; sub < 7; ++sub) {
    const ushort_t* brow = ckT + (size_t)(sub * 16 + n16) * KTOT + quad * 8;
    f32x4 acc = {0, 0, 0, 0};
#pragma unroll
    for (int ks = 0; ks < 7; ++ks)
      acc = __builtin_amdgcn_mfma_f32_16x16x32_bf16(afa[ks], *(const short8*)(brow + ks * 32), acc, 0, 0, 0);
#pragma unroll
    for (int ks = 0; ks < 4; ++ks)
      acc = __builtin_amdgcn_mfma_f32_16x16x32_bf16(afr[ks], *(const short8*)(brow + KAV + ks * 32), acc, 0, 0, 0);
    const int col = sub * 16 + n16;
    if (col < 100) {
      const float bias = cbs[col];
#pragma unroll
      for (int r = 0; r < 4; ++r) {
        const int row = quad * 4 + r;
        const float c = mytanh(acc[r] + bias);
        const float u = s_u[wave][row][col];
        const float hv = bf2f(s_h[wave][row][col]);
        fin2[(size_t)(m0 + row) * DD + col] = u * hv + (1.0f - u) * c;
      }
    }
  }
}

// ---------------------------------------------------------------------------
// K3: attention readout -> mab[b][128] bf16 (zero-padded k>=100)
// (reverted to the round-2 version: the round-4 rewrite was neutral/negative)
// ---------------------------------------------------------------------------
__global__ __launch_bounds__(256) void k_attn(
    const float* __restrict__ fin2, const int* __restrict__ alias_,
    const float* __restrict__ mask,
    const float* __restrict__ w1, const float* __restrict__ w2,
    const float* __restrict__ nv, const float* __restrict__ nb,
    ushort_t* __restrict__ mab)
{
  __shared__ float s_seqh[NNODE * DD];
  __shared__ float s_m[NNODE * DD];
  __shared__ float s_last[DD];
  __shared__ float s_coef[NNODE];
  __shared__ int s_lastid;
  const int b = blockIdx.x, t = threadIdx.x;

  if (t == 0) {
    float s = 0.0f;
    for (int l = 0; l < LLEN; ++l) s += mask[b * LLEN + l];
    int rm = (int)(s + 0.5f);
    s_lastid = alias_[b * LLEN + rm - 1];
  }
  for (int idx = t; idx < NNODE * DD; idx += 256) {
    int l = idx / DD, d = idx - l * DD;
    int n = alias_[b * LLEN + l];
    s_seqh[idx] = fin2[((size_t)b * NNODE + n) * DD + d];
  }
  __syncthreads();

  if (t < DD) {
    const float* lh = fin2 + ((size_t)b * NNODE + s_lastid) * DD;
    float acc = 0.0f;
    for (int k = 0; k < DD; ++k) acc += lh[k] * w1[k * DD + t];
    s_last[t] = acc;
  }
  __syncthreads();

  {
    const int tx = t & 31, ty = t >> 5, cb4 = tx * 4;
    if (cb4 < DD) {
      float acc[8][4] = {};
      for (int k4 = 0; k4 < 25; ++k4) {
        float4 bv[4];
#pragma unroll
        for (int kk = 0; kk < 4; ++kk) bv[kk] = *(const float4*)(w2 + (size_t)(k4 * 4 + kk) * DD + cb4);
#pragma unroll
        for (int i = 0; i < 8; ++i) {
          float4 a = *(const float4*)(&s_seqh[(ty * 8 + i) * DD + k4 * 4]);
#pragma unroll
          for (int kk = 0; kk < 4; ++kk) {
            float av_ = f4c(a, kk);
#pragma unroll
            for (int j = 0; j < 4; ++j) acc[i][j] += av_ * f4c(bv[kk], j);
          }
        }
      }
#pragma unroll
      for (int i = 0; i < 8; ++i) {
        int l = ty * 8 + i;
#pragma unroll
        for (int j = 0; j < 4; ++j) {
          int e = cb4 + j;
          s_m[l * DD + e] = sigm(acc[i][j] + s_last[e] + nb[e]);
        }
      }
    }
  }
  __syncthreads();

  if (t < LLEN) {
    float acc = 0.0f;
    for (int e = 0; e < DD; ++e) acc += s_m[t * DD + e] * nv[e];
    s_coef[t] = acc * mask[b * LLEN + t];
  }
  __syncthreads();

  if (t < DD) {
    float acc = 0.0f;
    for (int l = 0; l < LLEN; ++l) acc += s_coef[l] * s_seqh[l * DD + t];
    mab[(size_t)b * KP + t] = f2bf(acc);
  } else if (t < KP) {
    mab[(size_t)b * KP + t] = 0;
  }
}

// ---------------------------------------------------------------------------
// K4: logits = mab @ eb2[1:]^T via MFMA — long-burst store tiling.
//
// Evidence through round 4: time tracks store-run length, not reads
// (FETCH 50->6.8 MB: no effect), not occupancy (35->54%: got WORSE), not
// MFMA/VALU (3%/10%). Effective write BW: 512B runs -> 1.6 TB/s,
// 256B -> 1.4, 64B -> 1.4 w/ 1.6x amplification. Diagnosis: DRAM page
// locality — every run sits at a ~200KB row stride, so short runs waste
// page activations.
//
// Retile: block = 16 rows x 512 cols (one 128-col cblk per wave).
// C tile 16x512 f32 = 32 KB LDS -> stores are 2 KB contiguous per row
// (block-wide float4 store, 2 rows/iter) = 4x longer bursts.
// XCD-ownership now partitions col-GROUPS (cg = 4 cblks = 512 cols):
// 98 groups split 13/13/12/... across 8 XCDs (bijective), stripe (row
// group 0..31) fastest-varying -> per-XCD eb2 slice <= 1.7 MB L2-resident.
// Grid = 8 * 13 * 32 = 3328; invalid (xcd,lg) combos exit early.
// ---------------------------------------------------------------------------
__global__ __launch_bounds__(256) void k_logits_mfma(
    const ushort_t* __restrict__ eb2, const ushort_t* __restrict__ mab,
    float* __restrict__ out, float* __restrict__ sump)
{
  __shared__ float s_o[16][512];   // block C tile: 16 rows x 512 cols
  const int t = threadIdx.x;
  const int wave = t >> 6, lane = t & 63;
  const int n16 = lane & 15, quad = lane >> 4;
  const int bid = blockIdx.x;
  const int xcd = bid & 7;
  const int j = bid >> 3;                    // 0..415
  const int grpl = j >> 5;                   // local col-group 0..12
  const int lgmax = (xcd < 2) ? 13 : 12;     // 98 = 2*13 + 6*12
  if (grpl >= lgmax) return;
  const int stripe = j & 31;                 // fast-varying: 32 row-stripes
  const int cg = ((xcd < 2) ? xcd * 13 : 26 + (xcd - 2) * 12) + grpl; // 0..97
  const int m0 = stripe * 16;
  const int cblk = cg * 4 + wave;            // this wave's 128-col block

  short8 afr[4];
  const ushort_t* abase = mab + (size_t)(m0 + n16) * KP + quad * 8;
#pragma unroll
  for (int ks = 0; ks < 4; ++ks) afr[ks] = *(const short8*)(abase + ks * 32);

  float s[4] = {0.0f, 0.0f, 0.0f, 0.0f};
  if (cblk < NCB) {
#pragma unroll
    for (int sub = 0; sub < 8; ++sub) {
      const int c = cblk * 128 + sub * 16 + n16;
      const ushort_t* bbase = eb2 + (size_t)((c < NM1) ? (c + 1) : 0) * KP + quad * 8;
      f32x4 acc = {0.0f, 0.0f, 0.0f, 0.0f};
#pragma unroll
      for (int ks = 0; ks < 4; ++ks) {
        short8 bfr = *(const short8*)(bbase + ks * 32);
        acc = __builtin_amdgcn_mfma_f32_16x16x32_bf16(afr[ks], bfr, acc, 0, 0, 0);
      }
#pragma unroll
      for (int r = 0; r < 4; ++r) {
        s_o[quad * 4 + r][wave * 128 + sub * 16 + n16] = acc[r];
        if (c < NM1) s[r] += __expf(acc[r] - SHIFT);
      }
    }
  }
  __syncthreads();

  // store: 8 iters x (2 rows x 2048 B contiguous runs)
  float* lgp = out + 1;
  const int half = t >> 7, tc = t & 127;
#pragma unroll
  for (int it = 0; it < 8; ++it) {
    const int row = it * 2 + half;
    const size_t gr = m0 + row;
    f32x4 v = *(const f32x4*)&s_o[row][tc * 4];
    const int c0 = cg * 512 + tc * 4;
    if (c0 + 3 < NM1) {
      __builtin_nontemporal_store(v, (f32x4*)(lgp + gr * NM1 + c0));
    } else {
#pragma unroll
      for (int e = 0; e < 4; ++e)
        if (c0 + e < NM1)
          __builtin_nontemporal_store(v[e], lgp + gr * NM1 + c0 + e);
    }
  }

  if (cblk < NCB) {
    const int row0 = m0 + quad * 4;
#pragma unroll
    for (int r = 0; r < 4; ++r) {
      float x = s[r];
      x += __shfl_xor(x, 1, 64);
      x += __shfl_xor(x, 2, 64);
      x += __shfl_xor(x, 4, 64);
      x += __shfl_xor(x, 8, 64);
      if (n16 == 0) sump[(size_t)(row0 + r) * NCB + cblk] = x;
    }
  }
}

// ---------------------------------------------------------------------------
// K5: rowterm[r] = logits[r][tar[r]-1] - (log(sum) + SHIFT)
// ---------------------------------------------------------------------------
__global__ __launch_bounds__(64) void k_lse(
    const float* __restrict__ sump, const float* __restrict__ out,
    const int* __restrict__ tar, float* __restrict__ rowterm)
{
  const int r = blockIdx.x, t = threadIdx.x;
  float s = 0.0f;
  for (int i = t; i < NCB; i += 64) s += sump[(size_t)r * NCB + i];
  for (int m = 1; m < 64; m <<= 1) s += __shfl_xor(s, m, 64);
  if (t == 0) {
    int label = tar[r] - 1;
    const float* lg = out + 1;
    rowterm[r] = lg[(size_t)r * NM1 + label] - (logf(s) + SHIFT);
  }
}

// ---------------------------------------------------------------------------
// K6: loss = -mean(rowterm)
// ---------------------------------------------------------------------------
__global__ __launch_bounds__(256) void k_loss(
    const float* __restrict__ rowterm, float* __restrict__ out)
{
  const int t = threadIdx.x;
  __shared__ float red[4];
  float s = rowterm[t] + rowterm[t + 256];
  for (int m = 1; m < 64; m <<= 1) s += __shfl_xor(s, m, 64);
  if ((t & 63) == 0) red[t >> 6] = s;
  __syncthreads();
  if (t == 0) out[0] = -(red[0] + red[1] + red[2] + red[3]) / (float)BB;
}

// ---------------------------------------------------------------------------
extern "C" void kernel_launch(void* const* d_in, const int* in_sizes, int n_in,
                              void* d_out, int out_size, void* d_ws, size_t ws_size,
                              hipStream_t stream)
{
  (void)in_sizes; (void)n_in; (void)out_size; (void)ws_size;
  const float* adj_in  = (const float*)d_in[0];
  const float* adj_out = (const float*)d_in[1];
  const int*   item    = (const int*)d_in[2];
  const int*   alias_  = (const int*)d_in[3];
  const float* mask    = (const float*)d_in[4];
  const int*   tar     = (const int*)d_in[5];
  const float* emb     = (const float*)d_in[6];
  const float* W_in    = (const float*)d_in[7];
  const float* b_in    = (const float*)d_in[8];
  const float* W_out   = (const float*)d_in[9];
  const float* b_out   = (const float*)d_in[10];
  const float* gk      = (const float*)d_in[11];
  const float* gb      = (const float*)d_in[12];
  const float* ck      = (const float*)d_in[13];
  const float* cbs     = (const float*)d_in[14];
  const float* w1      = (const float*)d_in[15];
  const float* w2      = (const float*)d_in[16];
  const float* nv      = (const float*)d_in[17];
  const float* nb      = (const float*)d_in[18];
  float* out = (float*)d_out;

  // Workspace layout, ushort units.
  ushort_t* usw = (ushort_t*)d_ws;
  ushort_t* eb2  = usw;                    // 50000*128     = 6,400,000
  ushort_t* avb  = usw + 6400000;          // 32768*224     = 7,340,032
  ushort_t* WioT = usw + 13740032;         // 208*128       = 26,624
  ushort_t* gkT  = usw + 13766656;         // 208*352       = 73,216
  ushort_t* ckT  = usw + 13839872;         // 112*352       = 39,424
  ushort_t* mab  = usw + 13879296;         // 512*128       = 65,536
  float* fpool   = (float*)(usw + 13944832);
  float* fin2    = fpool;                  // 32768*100     = 3,276,800
  float* sump    = fpool + 3276800;        // 512*391       = 200,192
  float* rowterm = fpool + 3276800 + 200192;   // 512

  k_cvt_emb2<<<dim3(6250), 256, 0, stream>>>(emb, eb2);
  k_cvt_w   <<<dim3(287, 3), 256, 0, stream>>>(W_in, W_out, gk, ck, WioT, gkT, ckT);
  k_fio_av  <<<dim3(512), 256, 0, stream>>>(eb2, item, WioT, b_in, b_out, adj_in, adj_out, avb);
  k_gru_mfma<<<dim3(512), 256, 0, stream>>>(avb, eb2, item, gkT, gb, ckT, cbs, fin2);
  k_attn    <<<dim3(512), 256, 0, stream>>>(fin2, alias_, mask, w1, w2, nv, nb, mab);
  k_logits_mfma<<<dim3(3328), 256, 0, stream>>>(eb2, mab, out, sump);
  k_lse     <<<dim3(512), 64, 0, stream>>>(sump, out, tar, rowterm);
  k_loss    <<<dim3(1), 256, 0, stream>>>(rowterm, out);
}